// Round 2
// baseline (86.104 us; speedup 1.0000x reference)
//
#include <hip/hip_runtime.h>
#include <hip/hip_bf16.h>

using bf16x8  = __attribute__((ext_vector_type(8))) short;
using f32x4   = __attribute__((ext_vector_type(4))) float;
using ushort8 = __attribute__((ext_vector_type(8))) unsigned short;
using uint2v  = __attribute__((ext_vector_type(2))) unsigned int;

#define BB   32
#define CIN  128
#define COUT 128
#define PODS 2
#define HIN  56
#define WIN  56
#define HW   4096   // 64*64 padded spatial (flat index = kw*64 + kh, TRANSPOSED)

__device__ __forceinline__ unsigned short bf16bits(float v) {
  __hip_bfloat16 h = __float2bfloat16(v);
  return reinterpret_cast<unsigned short&>(h);
}
__device__ __forceinline__ float bits2f(unsigned short u) {
  return __uint_as_float(((unsigned)u) << 16);
}

template<int LEN>
__device__ __forceinline__ void fwht_stage(float (&a)[64]) {
  #pragma unroll
  for (int i = 0; i < 64; i += 2*LEN) {
    #pragma unroll
    for (int j = 0; j < LEN; ++j) {
      float u = a[i+j], v = a[i+j+LEN];
      a[i+j]     = u + v;
      a[i+j+LEN] = u - v;
    }
  }
}
__device__ __forceinline__ void fwht64(float (&a)[64]) {
  fwht_stage<1>(a); fwht_stage<2>(a); fwht_stage<4>(a);
  fwht_stage<8>(a); fwht_stage<16>(a); fwht_stage<32>(a);
}

// Wave-private 64x64 transpose via LDS. t rows padded to 66 floats:
// writes t[lane][w]: bank stride 66 -> 2-way conflict (free, m136);
// reads t[k][lane]: lane-consecutive -> conflict-free.
__device__ __forceinline__ void transpose64(float (&a)[64], float (*t)[66], int lane) {
  #pragma unroll
  for (int w = 0; w < 64; ++w) t[lane][w] = a[w];
  asm volatile("s_waitcnt lgkmcnt(0)" ::: "memory");
  #pragma unroll
  for (int k = 0; k < 64; ++k) a[k] = t[k][lane];
}

// ---- forward 2D FWHT per (b,c); pad 56x56 -> 64x64; write bf16 F[b][c][kw][kh] ----
// lane owns x row h=lane (vectorized float4 loads); fwht over w; transpose;
// fwht over h; lane now owns column kw=lane -> contiguous row of [kw][kh] layout.
__global__ __launch_bounds__(64) void k_fwht_fwd(const float* __restrict__ x,
                                                 unsigned short* __restrict__ F) {
  const int bc   = blockIdx.x;
  const int lane = threadIdx.x;

  float a[64];
  if (lane < HIN) {
    const float4* xr = reinterpret_cast<const float4*>(x + (size_t)bc*(HIN*WIN) + lane*WIN);
    #pragma unroll
    for (int j = 0; j < 14; ++j) {
      float4 v = xr[j];
      a[j*4+0] = v.x; a[j*4+1] = v.y; a[j*4+2] = v.z; a[j*4+3] = v.w;
    }
    #pragma unroll
    for (int w = WIN; w < 64; ++w) a[w] = 0.f;
  } else {
    #pragma unroll
    for (int w = 0; w < 64; ++w) a[w] = 0.f;
  }

  fwht64(a);                       // transform over w (thread-local)
  __shared__ float t[64][66];
  transpose64(a, t, lane);         // thread now owns column w=lane over h
  fwht64(a);                       // transform over h

  // store row kw=lane of [kw][kh]: 64 contiguous bf16 = one 128B line per thread
  unsigned short* Fp = F + (size_t)bc * HW + lane*64;
  #pragma unroll
  for (int j = 0; j < 8; ++j) {
    ushort8 v;
    #pragma unroll
    for (int e = 0; e < 8; ++e) v[e] = bf16bits(a[j*8 + e]);
    *reinterpret_cast<ushort8*>(Fp + j*8) = v;
  }
}

// ---- mixing: f6[b,o,hw] = softthr( sum_p sum_i W[p,o,i]*F[b,i,hw]*v'[p,hw] ) ----
// hw is the TRANSPOSED flat index kw*64+kh -> lv gather re-indexed.
// W converted f32->bf16 in-block (cw is L2-resident, 128KB).
__global__ __launch_bounds__(256, 2) void k_mix(const unsigned short* F,    // may alias G
                                                const float* __restrict__ cw,
                                                const float* __restrict__ lv,
                                                const float* __restrict__ T,
                                                unsigned short* G) {
  const int b    = blockIdx.x >> 5;
  const int hwb  = blockIdx.x & 31;      // hw0 = hwb*128
  const int tid  = threadIdx.x;
  const int wave = tid >> 6;
  const int l    = tid & 63;

  __shared__ __align__(16) char Blds[PODS][32768];   // [pod][128 rows x 256B], XOR-swizzled

  // A fragments (conv_w) in registers, converted from f32: [pod][tm][kk]
  const int arow = l & 15;
  const int acol = (l >> 4) * 8;
  bf16x8 afr[PODS][2][4];
  #pragma unroll
  for (int p = 0; p < PODS; ++p)
    #pragma unroll
    for (int tm = 0; tm < 2; ++tm)
      #pragma unroll
      for (int kk = 0; kk < 4; ++kk) {
        int o = wave*32 + tm*16 + arow;
        size_t off = ((size_t)(p*COUT + o))*CIN + kk*32 + acol;
        float4 w0 = *reinterpret_cast<const float4*>(cw + off);
        float4 w1 = *reinterpret_cast<const float4*>(cw + off + 4);
        bf16x8 fr;
        fr[0] = (short)bf16bits(w0.x); fr[1] = (short)bf16bits(w0.y);
        fr[2] = (short)bf16bits(w0.z); fr[3] = (short)bf16bits(w0.w);
        fr[4] = (short)bf16bits(w1.x); fr[5] = (short)bf16bits(w1.y);
        fr[6] = (short)bf16bits(w1.z); fr[7] = (short)bf16bits(w1.w);
        afr[p][tm][kk] = fr;
      }

  // stage B tiles: Blds[p][hw_local][i] bf16 (row = 256B), v-scaled
  const int hwl  = (wave & 1)*64 + l;     // 0..127
  const int ib   = (wave >> 1)*64;        // i half
  const int hwg  = hwb*128 + hwl;
  // lv is [p][kh][kw]; our flat hw = kw*64 + kh
  const int ivs  = (hwg & 63)*64 + (hwg >> 6);
  const float v0 = expf(lv[ivs]);
  const float v1 = expf(lv[HW + ivs]);
  const unsigned short* Fb = F + (size_t)b * CIN * HW;
  const int rowbase = hwl * 256;
  const int sw      = (hwl & 7) << 4;
  #pragma unroll
  for (int it = 0; it < 16; ++it) {
    int i0 = ib + it*4;
    float f0 = bits2f(Fb[(size_t)(i0+0)*HW + hwg]);
    float f1 = bits2f(Fb[(size_t)(i0+1)*HW + hwg]);
    float f2 = bits2f(Fb[(size_t)(i0+2)*HW + hwg]);
    float f3 = bits2f(Fb[(size_t)(i0+3)*HW + hwg]);
    int boff = rowbase + ((i0*2) ^ sw);
    {
      unsigned r0 = (unsigned)bf16bits(f0*v0) | ((unsigned)bf16bits(f1*v0) << 16);
      unsigned r1 = (unsigned)bf16bits(f2*v0) | ((unsigned)bf16bits(f3*v0) << 16);
      uint2v val = {r0, r1};
      *reinterpret_cast<uint2v*>(&Blds[0][boff]) = val;
    }
    {
      unsigned r0 = (unsigned)bf16bits(f0*v1) | ((unsigned)bf16bits(f1*v1) << 16);
      unsigned r1 = (unsigned)bf16bits(f2*v1) | ((unsigned)bf16bits(f3*v1) << 16);
      uint2v val = {r0, r1};
      *reinterpret_cast<uint2v*>(&Blds[1][boff]) = val;
    }
  }
  __syncthreads();

  // MFMA: per wave 2 tm x 8 t x 4 kk x 2 pods
  f32x4 acc[2][8];
  #pragma unroll
  for (int tm = 0; tm < 2; ++tm)
    #pragma unroll
    for (int t = 0; t < 8; ++t)
      acc[tm][t] = (f32x4){0.f, 0.f, 0.f, 0.f};

  #pragma unroll
  for (int t = 0; t < 8; ++t) {
    int row = t*16 + (l & 15);
    int rb  = row * 256;
    int s2  = (row & 7) << 4;
    #pragma unroll
    for (int kk = 0; kk < 4; ++kk) {
      int cb = (kk*64 + (l >> 4)*16) ^ s2;
      bf16x8 b0 = *reinterpret_cast<const bf16x8*>(&Blds[0][rb + cb]);
      bf16x8 b1 = *reinterpret_cast<const bf16x8*>(&Blds[1][rb + cb]);
      #pragma unroll
      for (int tm = 0; tm < 2; ++tm) {
        acc[tm][t] = __builtin_amdgcn_mfma_f32_16x16x32_bf16(afr[0][tm][kk], b0, acc[tm][t], 0, 0, 0);
        acc[tm][t] = __builtin_amdgcn_mfma_f32_16x16x32_bf16(afr[1][tm][kk], b1, acc[tm][t], 0, 0, 0);
      }
    }
  }

  // soft-threshold + store bf16
  unsigned short* Gb = G + (size_t)b * COUT * HW + hwb*128;
  #pragma unroll
  for (int tm = 0; tm < 2; ++tm) {
    #pragma unroll
    for (int r = 0; r < 4; ++r) {
      int o = wave*32 + tm*16 + (l >> 4)*4 + r;
      float th = fmaxf(T[o], 0.f);
      #pragma unroll
      for (int t = 0; t < 8; ++t) {
        float f = acc[tm][t][r];
        float m = fabsf(f) - th;
        m = m > 0.f ? m : 0.f;
        Gb[(size_t)o*HW + t*16 + (l & 15)] = bf16bits(copysignf(m, f));
      }
    }
  }
}

// ---- inverse 2D FWHT per (b,o), /4096, crop, + x ----
// G tile stored [kw][kh] (spatial transpose). lane vec-loads row u=lane;
// fwht over v; transpose; fwht over u. Result: thread owns y row h=lane
// over all w -> fully vectorized float4 stores with residual add.
__global__ __launch_bounds__(64) void k_ifwht(const unsigned short* __restrict__ G,
                                              const float* __restrict__ x,
                                              float* __restrict__ y) {
  const int bo   = blockIdx.x;
  const int lane = threadIdx.x;
  const unsigned short* Gp = G + (size_t)bo * HW + lane*64;

  float a[64];
  #pragma unroll
  for (int j = 0; j < 8; ++j) {
    ushort8 g = *reinterpret_cast<const ushort8*>(Gp + j*8);
    #pragma unroll
    for (int e = 0; e < 8; ++e) a[j*8+e] = bits2f(g[e]);
  }

  fwht64(a);                       // over fast axis (kh)
  __shared__ float t[64][66];
  transpose64(a, t, lane);         // thread now owns fixed kh=lane over kw
  fwht64(a);                       // over kw -> y row h=lane over w (x4096)

  if (lane < HIN) {
    const float4* xr = reinterpret_cast<const float4*>(x + (size_t)bo*(HIN*WIN) + lane*WIN);
    float4*       yr = reinterpret_cast<float4*>      (y + (size_t)bo*(HIN*WIN) + lane*WIN);
    #pragma unroll
    for (int w4 = 0; w4 < 14; ++w4) {
      float4 xv = xr[w4];
      float4 r;
      r.x = a[w4*4+0]*(1.f/4096.f) + xv.x;
      r.y = a[w4*4+1]*(1.f/4096.f) + xv.y;
      r.z = a[w4*4+2]*(1.f/4096.f) + xv.z;
      r.w = a[w4*4+3]*(1.f/4096.f) + xv.w;
      yr[w4] = r;
    }
  }
}

extern "C" void kernel_launch(void* const* d_in, const int* in_sizes, int n_in,
                              void* d_out, int out_size, void* d_ws, size_t ws_size,
                              hipStream_t stream) {
  const float* x  = (const float*)d_in[0];
  const float* cw = (const float*)d_in[1];
  const float* lv = (const float*)d_in[2];
  const float* T  = (const float*)d_in[3];
  float* y = (float*)d_out;

  char* ws = (char*)d_ws;
  const size_t szF = (size_t)BB * CIN * HW * 2;   // 33.5 MB
  const size_t szG = (size_t)BB * COUT * HW * 2;  // 33.5 MB

  unsigned short* F  = (unsigned short*)ws;
  // alias G onto F if workspace is tight (safe: each k_mix block reads only its
  // own (b, hw-slice) of F — all reads retire before its epilogue writes the
  // same (b, hw-slice) of G; blocks touch disjoint slices)
  unsigned short* G  = (ws_size >= szF + szG)
                     ? (unsigned short*)(ws + szF) : F;

  k_fwht_fwd<<<dim3(BB*CIN),  dim3(64),  0, stream>>>(x, F);
  k_mix     <<<dim3(BB*32),   dim3(256), 0, stream>>>(F, cw, lv, T, G);
  k_ifwht   <<<dim3(BB*COUT), dim3(64),  0, stream>>>(G, x, y);
}

// Round 3
// 69.834 us; speedup vs baseline: 1.2330x; 1.2330x over previous
//
#include <hip/hip_runtime.h>
#include <hip/hip_bf16.h>

using bf16x8  = __attribute__((ext_vector_type(8))) short;
using f32x4   = __attribute__((ext_vector_type(4))) float;
using ushort8 = __attribute__((ext_vector_type(8))) unsigned short;
using uint2v  = __attribute__((ext_vector_type(2))) unsigned int;

#define BB   32
#define CIN  128
#define COUT 128
#define PODS 2
#define HIN  56
#define WIN  56
#define HW   4096   // 64*64 padded spatial, natural [kh][kw] flat index

__device__ __forceinline__ unsigned short bf16bits(float v) {
  __hip_bfloat16 h = __float2bfloat16(v);
  return reinterpret_cast<unsigned short&>(h);
}
__device__ __forceinline__ float bits2f(unsigned short u) {
  return __uint_as_float(((unsigned)u) << 16);
}

template<int LEN>
__device__ __forceinline__ void fwht_stage(float (&a)[64]) {
  #pragma unroll
  for (int i = 0; i < 64; i += 2*LEN) {
    #pragma unroll
    for (int j = 0; j < LEN; ++j) {
      float u = a[i+j], v = a[i+j+LEN];
      a[i+j]     = u + v;
      a[i+j+LEN] = u - v;
    }
  }
}
__device__ __forceinline__ void fwht64(float (&a)[64]) {
  fwht_stage<1>(a); fwht_stage<2>(a); fwht_stage<4>(a);
  fwht_stage<8>(a); fwht_stage<16>(a); fwht_stage<32>(a);
}

#define LDS_WAIT() asm volatile("s_waitcnt lgkmcnt(0)" ::: "memory")

// ---- forward 2D FWHT per (b,c); pad 56x56 -> 64x64; write bf16 F[b][c][kh][kw] ----
// All global accesses lane-consecutive. Single wave per block.
__global__ __launch_bounds__(64) void k_fwht_fwd(const float* __restrict__ x,
                                                 unsigned short* __restrict__ F) {
  const int bc   = blockIdx.x;
  const int lane = threadIdx.x;

  __shared__ __align__(16) char smem[64*68*4];     // f32 t[64][68] aliased by bf16 tile
  float (*t)[68] = reinterpret_cast<float(*)[68]>(smem);

  // coalesced x load: lane = w column; 56 instrs x 224B contiguous
  float a[64];
  #pragma unroll
  for (int h = 0; h < 64; ++h) a[h] = 0.f;
  if (lane < WIN) {
    const float* xp = x + (size_t)bc*(HIN*WIN) + lane;
    #pragma unroll
    for (int h = 0; h < HIN; ++h) a[h] = xp[h*WIN];
  }

  fwht64(a);                                   // transform over h (lane owns w=lane)

  // transpose: write column lane (conflict-free), read row lane (float4, spread)
  #pragma unroll
  for (int k = 0; k < 64; ++k) t[k][lane] = a[k];
  LDS_WAIT();
  #pragma unroll
  for (int w4 = 0; w4 < 16; ++w4) {
    float4 v = *reinterpret_cast<const float4*>(&t[lane][w4*4]);
    a[w4*4+0] = v.x; a[w4*4+1] = v.y; a[w4*4+2] = v.z; a[w4*4+3] = v.w;
  }

  fwht64(a);                                   // transform over w (lane owns kh=lane)

  // bf16 staging: semantic tile[kh][kw] at byte kh*128 + kw*2, chunk-XOR-swizzled
  #pragma unroll
  for (int j = 0; j < 8; ++j) {
    ushort8 v;
    #pragma unroll
    for (int e = 0; e < 8; ++e) v[e] = bf16bits(a[j*8 + e]);
    *reinterpret_cast<ushort8*>(&smem[lane*128 + ((j*16) ^ ((lane&7)<<4))]) = v;
  }
  LDS_WAIT();

  // coalesced F store: 8 instrs x 1KB contiguous
  unsigned short* Fp = F + (size_t)bc * HW;
  #pragma unroll
  for (int jj = 0; jj < 8; ++jj) {
    int r     = jj*8 + (lane >> 3);
    int inner = (lane & 7) * 16;
    ushort8 v = *reinterpret_cast<const ushort8*>(&smem[r*128 + (inner ^ ((r&7)<<4))]);
    *reinterpret_cast<ushort8*>(Fp + jj*512 + lane*8) = v;
  }
}

// ---- mixing: f6[b,o,hw] = softthr( sum_p sum_i W[p,o,i]*F[b,i,hw]*v[p,hw] ) ----
__global__ __launch_bounds__(256, 2) void k_mix(const unsigned short* F,    // may alias G
                                                const float* __restrict__ cw,
                                                const float* __restrict__ lv,
                                                const float* __restrict__ T,
                                                unsigned short* G) {
  const int b    = blockIdx.x >> 5;
  const int hwb  = blockIdx.x & 31;      // hw0 = hwb*128
  const int tid  = threadIdx.x;
  const int wave = tid >> 6;
  const int l    = tid & 63;

  __shared__ __align__(16) char Blds[PODS][32768];   // [pod][128 rows x 256B], XOR-swizzled

  // A fragments (conv_w) in registers, converted from f32: [pod][tm][kk]
  const int arow = l & 15;
  const int acol = (l >> 4) * 8;
  bf16x8 afr[PODS][2][4];
  #pragma unroll
  for (int p = 0; p < PODS; ++p)
    #pragma unroll
    for (int tm = 0; tm < 2; ++tm)
      #pragma unroll
      for (int kk = 0; kk < 4; ++kk) {
        int o = wave*32 + tm*16 + arow;
        size_t off = ((size_t)(p*COUT + o))*CIN + kk*32 + acol;
        float4 w0 = *reinterpret_cast<const float4*>(cw + off);
        float4 w1 = *reinterpret_cast<const float4*>(cw + off + 4);
        bf16x8 fr;
        fr[0] = (short)bf16bits(w0.x); fr[1] = (short)bf16bits(w0.y);
        fr[2] = (short)bf16bits(w0.z); fr[3] = (short)bf16bits(w0.w);
        fr[4] = (short)bf16bits(w1.x); fr[5] = (short)bf16bits(w1.y);
        fr[6] = (short)bf16bits(w1.z); fr[7] = (short)bf16bits(w1.w);
        afr[p][tm][kk] = fr;
      }

  // stage B tiles: Blds[p][hw_local][i] bf16 (row = 256B), v-scaled
  const int hwl  = (wave & 1)*64 + l;     // 0..127
  const int ib   = (wave >> 1)*64;        // i half
  const int hwg  = hwb*128 + hwl;
  const float v0 = expf(lv[hwg]);         // natural [kh][kw] layout now
  const float v1 = expf(lv[HW + hwg]);
  const unsigned short* Fb = F + (size_t)b * CIN * HW;
  const int rowbase = hwl * 256;
  const int sw      = (hwl & 7) << 4;
  #pragma unroll
  for (int it = 0; it < 16; ++it) {
    int i0 = ib + it*4;
    float f0 = bits2f(Fb[(size_t)(i0+0)*HW + hwg]);
    float f1 = bits2f(Fb[(size_t)(i0+1)*HW + hwg]);
    float f2 = bits2f(Fb[(size_t)(i0+2)*HW + hwg]);
    float f3 = bits2f(Fb[(size_t)(i0+3)*HW + hwg]);
    int boff = rowbase + ((i0*2) ^ sw);
    {
      unsigned r0 = (unsigned)bf16bits(f0*v0) | ((unsigned)bf16bits(f1*v0) << 16);
      unsigned r1 = (unsigned)bf16bits(f2*v0) | ((unsigned)bf16bits(f3*v0) << 16);
      uint2v val = {r0, r1};
      *reinterpret_cast<uint2v*>(&Blds[0][boff]) = val;
    }
    {
      unsigned r0 = (unsigned)bf16bits(f0*v1) | ((unsigned)bf16bits(f1*v1) << 16);
      unsigned r1 = (unsigned)bf16bits(f2*v1) | ((unsigned)bf16bits(f3*v1) << 16);
      uint2v val = {r0, r1};
      *reinterpret_cast<uint2v*>(&Blds[1][boff]) = val;
    }
  }
  __syncthreads();

  // MFMA: per wave 2 tm x 8 t x 4 kk x 2 pods
  f32x4 acc[2][8];
  #pragma unroll
  for (int tm = 0; tm < 2; ++tm)
    #pragma unroll
    for (int t = 0; t < 8; ++t)
      acc[tm][t] = (f32x4){0.f, 0.f, 0.f, 0.f};

  #pragma unroll
  for (int t = 0; t < 8; ++t) {
    int row = t*16 + (l & 15);
    int rb  = row * 256;
    int s2  = (row & 7) << 4;
    #pragma unroll
    for (int kk = 0; kk < 4; ++kk) {
      int cb = (kk*64 + (l >> 4)*16) ^ s2;
      bf16x8 b0 = *reinterpret_cast<const bf16x8*>(&Blds[0][rb + cb]);
      bf16x8 b1 = *reinterpret_cast<const bf16x8*>(&Blds[1][rb + cb]);
      #pragma unroll
      for (int tm = 0; tm < 2; ++tm) {
        acc[tm][t] = __builtin_amdgcn_mfma_f32_16x16x32_bf16(afr[0][tm][kk], b0, acc[tm][t], 0, 0, 0);
        acc[tm][t] = __builtin_amdgcn_mfma_f32_16x16x32_bf16(afr[1][tm][kk], b1, acc[tm][t], 0, 0, 0);
      }
    }
  }

  // soft-threshold + store bf16
  unsigned short* Gb = G + (size_t)b * COUT * HW + hwb*128;
  #pragma unroll
  for (int tm = 0; tm < 2; ++tm) {
    #pragma unroll
    for (int r = 0; r < 4; ++r) {
      int o = wave*32 + tm*16 + (l >> 4)*4 + r;
      float th = fmaxf(T[o], 0.f);
      #pragma unroll
      for (int t = 0; t < 8; ++t) {
        float f = acc[tm][t][r];
        float m = fabsf(f) - th;
        m = m > 0.f ? m : 0.f;
        Gb[(size_t)o*HW + t*16 + (l & 15)] = bf16bits(copysignf(m, f));
      }
    }
  }
}

// ---- inverse 2D FWHT per (b,o), /4096, crop, + x ----
// Coalesced G loads (1KB/instr), LDS-distributed transforms, coalesced y stores.
__global__ __launch_bounds__(64) void k_ifwht(const unsigned short* __restrict__ G,
                                              const float* __restrict__ x,
                                              float* __restrict__ y) {
  const int bo   = blockIdx.x;
  const int lane = threadIdx.x;

  __shared__ __align__(16) char smem[64*68*4];
  float (*t)[68] = reinterpret_cast<float(*)[68]>(smem);

  // coalesced G load -> f32 LDS tile t[kh][kw]
  const unsigned short* Gp = G + (size_t)bo * HW;
  #pragma unroll
  for (int jj = 0; jj < 8; ++jj) {
    ushort8 g = *reinterpret_cast<const ushort8*>(Gp + jj*512 + lane*8);
    int kh  = jj*8 + (lane >> 3);
    int kw0 = (lane & 7) * 8;
    float4 lo = {bits2f(g[0]), bits2f(g[1]), bits2f(g[2]), bits2f(g[3])};
    float4 hi = {bits2f(g[4]), bits2f(g[5]), bits2f(g[6]), bits2f(g[7])};
    *reinterpret_cast<float4*>(&t[kh][kw0])     = lo;
    *reinterpret_cast<float4*>(&t[kh][kw0 + 4]) = hi;
  }
  LDS_WAIT();

  // lane reads column kw=lane (conflict-free)
  float a[64];
  #pragma unroll
  for (int kh = 0; kh < 64; ++kh) a[kh] = t[kh][lane];

  fwht64(a);                                   // transform over kh -> V1[h][kw=lane]

  // transpose: write column lane, read row lane
  #pragma unroll
  for (int h = 0; h < 64; ++h) t[h][lane] = a[h];
  LDS_WAIT();
  #pragma unroll
  for (int w4 = 0; w4 < 16; ++w4) {
    float4 v = *reinterpret_cast<const float4*>(&t[lane][w4*4]);
    a[w4*4+0] = v.x; a[w4*4+1] = v.y; a[w4*4+2] = v.z; a[w4*4+3] = v.w;
  }

  fwht64(a);                                   // transform over kw -> V2[h=lane][w]

  // scale, write row lane back (float4, spread)
  #pragma unroll
  for (int w4 = 0; w4 < 16; ++w4) {
    float4 v = {a[w4*4+0]*(1.f/4096.f), a[w4*4+1]*(1.f/4096.f),
                a[w4*4+2]*(1.f/4096.f), a[w4*4+3]*(1.f/4096.f)};
    *reinterpret_cast<float4*>(&t[lane][w4*4]) = v;
  }
  LDS_WAIT();

  // coalesced residual + store: lane = w column; 56 instrs x 224B
  if (lane < WIN) {
    const float* xp = x + (size_t)bo*(HIN*WIN) + lane;
    float*       yp = y + (size_t)bo*(HIN*WIN) + lane;
    #pragma unroll
    for (int h = 0; h < HIN; ++h) {
      yp[h*WIN] = t[h][lane] + xp[h*WIN];
    }
  }
}

extern "C" void kernel_launch(void* const* d_in, const int* in_sizes, int n_in,
                              void* d_out, int out_size, void* d_ws, size_t ws_size,
                              hipStream_t stream) {
  const float* x  = (const float*)d_in[0];
  const float* cw = (const float*)d_in[1];
  const float* lv = (const float*)d_in[2];
  const float* T  = (const float*)d_in[3];
  float* y = (float*)d_out;

  char* ws = (char*)d_ws;
  const size_t szF = (size_t)BB * CIN * HW * 2;   // 33.5 MB
  const size_t szG = (size_t)BB * COUT * HW * 2;  // 33.5 MB

  unsigned short* F  = (unsigned short*)ws;
  // alias G onto F if workspace is tight (safe: each k_mix block reads only its
  // own (b, hw-slice) of F — all reads retire before its epilogue writes the
  // same (b, hw-slice) of G; blocks touch disjoint slices)
  unsigned short* G  = (ws_size >= szF + szG)
                     ? (unsigned short*)(ws + szF) : F;

  k_fwht_fwd<<<dim3(BB*CIN),  dim3(64),  0, stream>>>(x, F);
  k_mix     <<<dim3(BB*32),   dim3(256), 0, stream>>>(F, cw, lv, T, G);
  k_ifwht   <<<dim3(BB*COUT), dim3(64),  0, stream>>>(G, x, y);
}